// Round 6
// baseline (212.225 us; speedup 1.0000x reference)
//
#include <hip/hip_runtime.h>

// AdderNet forward: out[n,h,w,f] = sum_{dh,dw,c} |Xpad[n,h+dh,w+dw,c] - F[f,dh,dw,c]|
// N=8, H=W=32, C=32, c_out=64, k=3, pad=1. fp32.
//
// R6: single kernel (no prep) + 8x visibility probe.
// Thread = (c4 wave 0..7 [readfirstlane -> uniform], f lane 0..63). Lane keeps
// its filter slice (9 taps x 4ch = 36 VGPR) gathered from native F. x rows are
// wave-uniform -> s_load_dwordx4 from native X; padding handled by
// block-uniform scalar branches (all xrow indices compile-time -> SGPRs).
// Cross-wave c4 reduction via LDS stride 10 (2-way bank conflicts = free):
// 4 ds_write_b64 + 8 ds_read_b32 per lane. Grid 1024 = (n:8,h:32,wb:4).
// PROBE: same kernel at grid 8192 (blockIdx&1023) -> 8x dur surfaces it in
// rocprof top-5 with real counters; duplicate blocks write identical bytes.

__global__ __launch_bounds__(512, 4) void adder_main(const float* __restrict__ X,
                                                     const float* __restrict__ Fg,
                                                     float* __restrict__ out) {
    __shared__ float part[8 * 64 * 10];   // [c4][f][w pad10] = 20480 B

    const int b  = blockIdx.x & 1023;     // probe folding (grid 1024 or 8192)
    const int wb = b & 3;
    const int h  = (b >> 2) & 31;
    const int n  = b >> 7;
    const int w0 = wb * 8;

    const int tid = threadIdx.x;
    const int f   = tid & 63;
    const int c4  = __builtin_amdgcn_readfirstlane(tid >> 6);  // 0..7, uniform

    // Filter slice gather from native F[f][tap][c]: as float4 [f][9][8]
    float4 Freg[9];
    const float4* Fq = (const float4*)Fg;
    #pragma unroll
    for (int t = 0; t < 9; ++t)
        Freg[t] = Fq[f * 72 + t * 8 + c4];

    float acc[8];
    #pragma unroll
    for (int w = 0; w < 8; ++w) acc[w] = 0.f;

    #pragma unroll
    for (int dh = 0; dh < 3; ++dh) {
        const int r = h + dh - 1;                 // block-uniform
        float4 xrow[10];                          // chunks wp = w0-1 .. w0+8
        #pragma unroll
        for (int k = 0; k < 10; ++k) xrow[k] = make_float4(0.f, 0.f, 0.f, 0.f);
        if ((unsigned)r < 32u) {                  // uniform branch
            // base at wp = w0 (always in-bounds); X as float4 [n][h][w][8]
            const float4* xr = (const float4*)X + (((n * 32 + r) * 32 + w0) * 8 + c4);
            #pragma unroll
            for (int k = 1; k <= 8; ++k) xrow[k] = xr[(k - 1) * 8];
            if (wb > 0) xrow[0] = xr[-8];         // wp = w0-1
            if (wb < 3) xrow[9] = xr[64];         // wp = w0+8
        }

        #pragma unroll
        for (int w = 0; w < 8; ++w) {
            #pragma unroll
            for (int dw = 0; dw < 3; ++dw) {
                float4 xv = xrow[w + dw];
                float4 fv = Freg[dh * 3 + dw];
                acc[w] += fabsf(xv.x - fv.x) + fabsf(xv.y - fv.y)
                        + fabsf(xv.z - fv.z) + fabsf(xv.w - fv.w);
            }
        }
    }

    // cross-wave (c4) reduction; stride 10 -> 2-way conflicts only (free)
    #pragma unroll
    for (int w = 0; w < 8; w += 2) {
        *(float2*)&part[(c4 * 64 + f) * 10 + w] = make_float2(acc[w], acc[w + 1]);
    }
    __syncthreads();

    const int fp = tid & 63;
    const int wq = tid >> 6;                      // 0..7
    float s = 0.f;
    #pragma unroll
    for (int cc = 0; cc < 8; ++cc)
        s += part[(cc * 64 + fp) * 10 + wq];

    out[(((size_t)n * 32 + h) * 32 + (w0 + wq)) * 64 + fp] = s;
}

extern "C" void kernel_launch(void* const* d_in, const int* in_sizes, int n_in,
                              void* d_out, int out_size, void* d_ws, size_t ws_size,
                              hipStream_t stream) {
    const float* X = (const float*)d_in[0];
    const float* F = (const float*)d_in[1];
    float* out = (float*)d_out;

    // real dispatch
    adder_main<<<dim3(1024), dim3(512), 0, stream>>>(X, F, out);
    // 8x probe (diagnostic this round only): identical per-block work/writes
    adder_main<<<dim3(8192), dim3(512), 0, stream>>>(X, F, out);
}

// Round 7
// 101.819 us; speedup vs baseline: 2.0843x; 2.0843x over previous
//
#include <hip/hip_runtime.h>

// AdderNet forward: out[n,h,w,f] = sum_{dh,dw,c} |Xpad[n,h+dh,w+dw,c] - F[f,dh,dw,c]|
// N=8, H=W=32, C=32, c_out=64, k=3, pad=1. fp32.
//
// R7: lane remap for coalescing. Wave = (fsub:8, c4:8), lane = fsub*8 + c4.
//  - filter load: 8x128B segments/instr (R6 had 64x16B -> L1 meltdown, probe-
//    verified: 155us @8x grid, VALUBusy 54%).
//  - X row load: one 128B segment/instr (8-way lane-duplicate, HW-merged),
//    straight to VGPRs. NO LDS anywhere in the kernel.
//  - c4 reduction: __shfl_xor butterfly over low 3 lane bits (replaces the
//    4-way-conflicted LDS epilogue R6 had: f*10%32 collides at f+16).
//  - stores: per-lane 4B, address set = 8 x 32B segments (coalescer merges).
// Block 256 = 4 waves = 32 filters; grid 2048 = (n:8, h:32, wb:4, fh:2).
// Per lane: 8 w x 9 taps x 4 ch = 576 VALU -> VALU-bound, ~9.2K cyc/SIMD.

__global__ __launch_bounds__(256, 4) void adder_fwd(const float* __restrict__ X,
                                                    const float* __restrict__ Fg,
                                                    float* __restrict__ out) {
    const int b  = blockIdx.x;
    const int fh = b & 1;
    const int wb = (b >> 1) & 3;
    const int h  = (b >> 3) & 31;
    const int n  = b >> 8;
    const int w0 = wb * 8;

    const int tid  = threadIdx.x;
    const int wave = tid >> 6;
    const int lane = tid & 63;
    const int fsub = lane >> 3;      // 0..7 : filter within wave
    const int c4   = lane & 7;       // 0..7 : channel chunk (low bits!)
    const int f    = fh * 32 + wave * 8 + fsub;

    // Filter slice: 9 taps x 4 ch in VGPRs. Per instr: 8 x 128B segments.
    const float4* Fq = (const float4*)Fg;      // F = [64][9][8] float4
    float4 Freg[9];
    #pragma unroll
    for (int t = 0; t < 9; ++t)
        Freg[t] = Fq[f * 72 + t * 8 + c4];

    float acc[8];
    #pragma unroll
    for (int w = 0; w < 8; ++w) acc[w] = 0.f;

    #pragma unroll
    for (int dh = 0; dh < 3; ++dh) {
        const int r = h + dh - 1;                    // block-uniform
        float4 xrow[10];                             // chunks w = w0-1 .. w0+8
        #pragma unroll
        for (int k = 0; k < 10; ++k) xrow[k] = make_float4(0.f, 0.f, 0.f, 0.f);
        if ((unsigned)r < 32u) {                     // uniform branch
            // X = [8][32][32][8] float4; addr indep of fsub -> 1 x 128B seg
            const float4* xr = (const float4*)X + (((n * 32 + r) * 32 + w0) * 8 + c4);
            #pragma unroll
            for (int k = 1; k <= 8; ++k) xrow[k] = xr[(k - 1) * 8];
            if (wb > 0) xrow[0] = xr[-8];
            if (wb < 3) xrow[9] = xr[64];
        }

        #pragma unroll
        for (int w = 0; w < 8; ++w) {
            #pragma unroll
            for (int dw = 0; dw < 3; ++dw) {
                float4 xv = xrow[w + dw];
                float4 fv = Freg[dh * 3 + dw];
                acc[w] += fabsf(xv.x - fv.x) + fabsf(xv.y - fv.y)
                        + fabsf(xv.z - fv.z) + fabsf(xv.w - fv.w);
            }
        }
    }

    // Reduce over c4 (low 3 lane bits): butterfly, all lanes end with full sums
    #pragma unroll
    for (int w = 0; w < 8; ++w) {
        acc[w] += __shfl_xor(acc[w], 1);
        acc[w] += __shfl_xor(acc[w], 2);
        acc[w] += __shfl_xor(acc[w], 4);
    }

    // Lane (fsub, c4) stores (f, w = w0 + c4): select acc[c4] via cndmask chain
    float val = acc[0];
    val = (c4 == 1) ? acc[1] : val;
    val = (c4 == 2) ? acc[2] : val;
    val = (c4 == 3) ? acc[3] : val;
    val = (c4 == 4) ? acc[4] : val;
    val = (c4 == 5) ? acc[5] : val;
    val = (c4 == 6) ? acc[6] : val;
    val = (c4 == 7) ? acc[7] : val;

    out[(((size_t)n * 32 + h) * 32 + (w0 + c4)) * 64 + f] = val;
}

extern "C" void kernel_launch(void* const* d_in, const int* in_sizes, int n_in,
                              void* d_out, int out_size, void* d_ws, size_t ws_size,
                              hipStream_t stream) {
    const float* X = (const float*)d_in[0];
    const float* F = (const float*)d_in[1];
    float* out = (float*)d_out;
    adder_fwd<<<dim3(2048), dim3(256), 0, stream>>>(X, F, out);
}